// Round 6
// baseline (384.017 us; speedup 1.0000x reference)
//
#include <hip/hip_runtime.h>
#include <math.h>

#define N 4096
#define DD 256
#define CAP 512      // per-column candidate capacity (~93 expected at T0=2.0)
#define RCAP 256     // per-row support capacity
#define LEAKY 0.2f
#define T0 2.0f      // fixed column-candidate threshold; exactness restored by rescan

// ---- monotone float<->uint map for atomicMax on floats ----
__device__ __forceinline__ unsigned fmap(float f){
  unsigned u = __float_as_uint(f);
  return (u & 0x80000000u) ? ~u : (u | 0x80000000u);
}
__device__ __forceinline__ float funmap(unsigned u){
  unsigned b = (u & 0x80000000u) ? (u & 0x7fffffffu) : ~u;
  return __uint_as_float(b);
}

// ---------------------------------------------------------------------------
// Row sparsemax (one block per row, row-major streaming read of cost):
//  - row tau (Michelot, exact), writes out_row
//  - beta[i,:] via LDS support list
//  - NEW: column candidates x > T0 appended to per-column lists, plus
//    atomicMax of colmax[j] over candidates (true max is a candidate
//    whenever M_j > T0; columns with M_j <= T0+1 are rescanned exactly).
// ---------------------------------------------------------------------------
__global__ __launch_bounds__(256) void k_row(const float* __restrict__ cost,
      const float* __restrict__ colvecs, float* __restrict__ out_row,
      float* __restrict__ beta, int* __restrict__ cnt,
      float* __restrict__ candv, int* __restrict__ candi,
      unsigned* __restrict__ colmax){
  const int i = blockIdx.x, t = threadIdx.x;
  const int w = t >> 6, lane = t & 63;
  __shared__ float s_red[4];
  __shared__ float s_M, s_tau, s_b;
  __shared__ int   s_cnt, s_cnt2;
  __shared__ float s_cv[RCAP];
  __shared__ int   s_cj[RCAP];

  const float4* row4 = (const float4*)(cost + (size_t)i * N);
  float4 x4[4];
  #pragma unroll
  for (int q = 0; q < 4; ++q){
    float4 v = row4[t + q * 256];
    x4[q] = make_float4(-v.x, -v.y, -v.z, -v.w);
  }

  // column candidate collection (independent of row sparsemax)
  #pragma unroll
  for (int q = 0; q < 4; ++q){
    const float* e = &x4[q].x;
    int jb = 4 * (t + q * 256);
    #pragma unroll
    for (int cc = 0; cc < 4; ++cc){
      float v = e[cc];
      if (v > T0){
        int j = jb + cc;
        int qq = atomicAdd(&cnt[j], 1);
        if (qq < CAP){ candv[(size_t)j * CAP + qq] = v; candi[(size_t)j * CAP + qq] = i; }
        atomicMax(&colmax[j], fmap(v));
      }
    }
  }

  float m = -3.4e38f;
  #pragma unroll
  for (int q = 0; q < 4; ++q)
    m = fmaxf(m, fmaxf(fmaxf(x4[q].x, x4[q].y), fmaxf(x4[q].z, x4[q].w)));
  for (int off = 32; off; off >>= 1) m = fmaxf(m, __shfl_xor(m, off));
  if (lane == 0) s_red[w] = m;
  if (t == 0){ s_cnt = 0; s_cnt2 = 0; }
  __syncthreads();
  if (t == 0) s_M = fmaxf(fmaxf(s_red[0], s_red[1]), fmaxf(s_red[2], s_red[3]));
  __syncthreads();
  const float M = s_M, th = M - 1.0f;

  #pragma unroll
  for (int q = 0; q < 4; ++q){
    const float* e = &x4[q].x;
    #pragma unroll
    for (int c = 0; c < 4; ++c){
      float v = e[c];
      if (v > th){ int p = atomicAdd(&s_cnt, 1); if (p < RCAP) s_cv[p] = v; }
    }
  }
  __syncthreads();
  int c = s_cnt;
  if (c <= RCAP){
    if (w == 0){
      float v[4];
      #pragma unroll
      for (int s = 0; s < 4; ++s){ int l = s * 64 + lane; v[s] = (l < c) ? s_cv[l] : -3.4e38f; }
      float tau = -3.0e38f;
      for (int it = 0; it < 40; ++it){
        float sum = 0.0f, cf = 0.0f;
        #pragma unroll
        for (int s = 0; s < 4; ++s) if (v[s] > tau){ sum += v[s]; cf += 1.0f; }
        for (int off = 32; off; off >>= 1){ sum += __shfl_xor(sum, off); cf += __shfl_xor(cf, off); }
        float nt = (sum - 1.0f) / cf;
        if (nt == tau) break;
        tau = nt;
      }
      if (lane == 0) s_tau = tau;
    }
    __syncthreads();
  } else {
    // fallback: block bisection on [M-1, M] (not taken for this input)
    float lo = th, hi = M;
    for (int it = 0; it < 40; ++it){
      float mid = 0.5f * (lo + hi);
      float part = 0.0f;
      #pragma unroll
      for (int q = 0; q < 4; ++q){
        const float* e = &x4[q].x;
        #pragma unroll
        for (int cc = 0; cc < 4; ++cc) part += fmaxf(e[cc] - mid, 0.0f);
      }
      for (int off = 32; off; off >>= 1) part += __shfl_xor(part, off);
      if (lane == 0) s_red[w] = part;
      __syncthreads();
      if (t == 0) s_b = s_red[0] + s_red[1] + s_red[2] + s_red[3];
      __syncthreads();
      if (s_b >= 1.0f) lo = mid; else hi = mid;
      __syncthreads();
    }
    if (t == 0) s_tau = lo;
    __syncthreads();
  }
  const float tau = s_tau;

  float4* orow4 = (float4*)(out_row + (size_t)i * N);
  #pragma unroll
  for (int q = 0; q < 4; ++q){
    float4 p;
    p.x = fmaxf(x4[q].x - tau, 0.0f);
    p.y = fmaxf(x4[q].y - tau, 0.0f);
    p.z = fmaxf(x4[q].z - tau, 0.0f);
    p.w = fmaxf(x4[q].w - tau, 0.0f);
    orow4[t + q * 256] = p;

    int jb = 4 * (t + q * 256);
    const float* e = &p.x;
    #pragma unroll
    for (int cc = 0; cc < 4; ++cc){
      if (e[cc] > 0.0f){
        int l = atomicAdd(&s_cnt2, 1);
        if (l < RCAP){ s_cv[l] = e[cc]; s_cj[l] = jb + cc; }
      }
    }
  }
  __syncthreads();
  int ns = min(s_cnt2, RCAP);
  float acc = 0.0f;
  #pragma unroll 4
  for (int l = 0; l < ns; ++l)
    acc += s_cv[l] * colvecs[(size_t)s_cj[l] * DD + t];
  beta[(size_t)i * DD + t] = acc;
}

// ---------------------------------------------------------------------------
// Mark columns whose T0-candidate list may be incomplete: no candidates,
// overflow, or M_j - 1 < T0. (cnt==0 checked first: colmax unset -> NaN.)
// ---------------------------------------------------------------------------
__global__ __launch_bounds__(256) void k_suspect(const int* __restrict__ cnt,
      const unsigned* __restrict__ colmax, int* __restrict__ scnt,
      int* __restrict__ slist){
  int j = blockIdx.x * 256 + threadIdx.x;
  int c = cnt[j];
  bool sus = (c == 0) || (c > CAP) || (funmap(colmax[j]) < T0 + 1.0f);
  if (sus){ int p = atomicAdd(scnt, 1); slist[p] = j; }
}

// ---------------------------------------------------------------------------
// Exact rescan of suspect columns (expected ~16; grid-stride, one block/col).
// Rebuilds the candidate list with the exact threshold M_j - 1.
// ---------------------------------------------------------------------------
__global__ __launch_bounds__(256) void k_rescan(const float* __restrict__ cost,
      const int* __restrict__ scnt, const int* __restrict__ slist,
      int* __restrict__ cnt, float* __restrict__ candv, int* __restrict__ candi){
  __shared__ float sred[4];
  const int t = threadIdx.x, w = t >> 6, lane = t & 63;
  const int ns = scnt[0];
  for (int s = blockIdx.x; s < ns; s += 64){
    const int j = slist[s];
    float m = -3.4e38f;
    for (int r = t; r < N; r += 256) m = fmaxf(m, -cost[(size_t)r * N + j]);
    for (int off = 32; off; off >>= 1) m = fmaxf(m, __shfl_xor(m, off));
    if (lane == 0) sred[w] = m;
    if (t == 0) atomicExch(&cnt[j], 0);
    __syncthreads();
    const float M = fmaxf(fmaxf(sred[0], sred[1]), fmaxf(sred[2], sred[3]));
    const float th = M - 1.0f;
    for (int r = t; r < N; r += 256){
      float x = -cost[(size_t)r * N + j];
      if (x > th){
        int q = atomicAdd(&cnt[j], 1);
        if (q < CAP){ candv[(size_t)j * CAP + q] = x; candi[(size_t)j * CAP + q] = r; }
      }
    }
    __syncthreads();
  }
}

// ---------------------------------------------------------------------------
// Column tau (Michelot on candidates, one wave per column) + alpha[j,:]
// ---------------------------------------------------------------------------
__global__ __launch_bounds__(256) void k_coltau(const int* __restrict__ cnt,
      const float* __restrict__ candv, const int* __restrict__ candi,
      const float* __restrict__ rowvecs, float* __restrict__ tau_out,
      float* __restrict__ alpha){
  const int t = threadIdx.x, w = t >> 6, lane = t & 63;
  const int j = blockIdx.x * 4 + w;
  const int c = min(cnt[j], CAP);
  const float* cv = candv + (size_t)j * CAP;
  const int*   ci = candi + (size_t)j * CAP;

  float v[8]; int id[8];
  #pragma unroll
  for (int s = 0; s < 8; ++s){
    int l = s * 64 + lane;
    v[s]  = (l < c) ? cv[l] : -3.4e38f;
    id[s] = (l < c) ? ci[l] : 0;
  }

  float tau = -3.0e38f;
  for (int it = 0; it < 40; ++it){
    float sum = 0.0f, cf = 0.0f;
    #pragma unroll
    for (int s = 0; s < 8; ++s) if (v[s] > tau){ sum += v[s]; cf += 1.0f; }
    for (int off = 32; off; off >>= 1){ sum += __shfl_xor(sum, off); cf += __shfl_xor(cf, off); }
    float nt = (sum - 1.0f) / cf;
    if (nt == tau) break;
    tau = nt;
  }
  if (lane == 0) tau_out[j] = tau;

  __shared__ float sup_v[4][CAP];
  __shared__ int   sup_i[4][CAP];
  int base = 0;
  #pragma unroll
  for (int s = 0; s < 8; ++s){
    bool pred = (v[s] > tau);
    unsigned long long mk = __ballot(pred);
    if (pred){
      int pos = base + __popcll(mk & ((1ULL << lane) - 1ULL));
      sup_v[w][pos] = v[s] - tau;
      sup_i[w][pos] = id[s];
    }
    base += __popcll(mk);
  }
  const int nsup = base;
  __builtin_amdgcn_wave_barrier();
  __asm__ volatile("s_waitcnt lgkmcnt(0)");

  float a0 = 0, a1 = 0, a2 = 0, a3 = 0;
  #pragma unroll 4
  for (int l = 0; l < nsup; ++l){
    float pp = sup_v[w][l];
    const float* ar = rowvecs + (size_t)sup_i[w][l] * DD;
    a0 += pp * ar[lane];        a1 += pp * ar[64 + lane];
    a2 += pp * ar[128 + lane];  a3 += pp * ar[192 + lane];
  }
  float* al = alpha + (size_t)j * DD;
  al[lane] = a0; al[64 + lane] = a1; al[128 + lane] = a2; al[192 + lane] = a3;
}

// ---------------------------------------------------------------------------
// G(x) = leaky_relu(x @ W + b); accumulate column sums for the means
// ---------------------------------------------------------------------------
__global__ __launch_bounds__(256) void k_G(const float* __restrict__ beta,
      const float* __restrict__ alpha, const float* __restrict__ W,
      const float* __restrict__ bG, float* __restrict__ vsum){
  int t = threadIdx.x, side = blockIdx.y, r0 = blockIdx.x * 16;
  const float* src = side ? alpha : beta;
  __shared__ float sB[16 * 256];
  #pragma unroll
  for (int k = 0; k < 16; ++k) sB[k * 256 + t] = src[(size_t)(r0 + k) * 256 + t];
  __syncthreads();
  float acc[16];
  float bg = bG[t];
  #pragma unroll
  for (int r = 0; r < 16; ++r) acc[r] = bg;
  const float4* sB4 = (const float4*)sB;
  for (int d4 = 0; d4 < 64; ++d4){
    int d = d4 * 4;
    float w0 = W[(size_t)d * 256 + t];
    float w1 = W[(size_t)(d + 1) * 256 + t];
    float w2 = W[(size_t)(d + 2) * 256 + t];
    float w3 = W[(size_t)(d + 3) * 256 + t];
    #pragma unroll
    for (int r = 0; r < 16; ++r){
      float4 s = sB4[r * 64 + d4];
      acc[r] += s.x * w0 + s.y * w1 + s.z * w2 + s.w * w3;
    }
  }
  float s = 0.0f;
  #pragma unroll
  for (int r = 0; r < 16; ++r){ float u = acc[r]; s += (u > 0.0f) ? u : LEAKY * u; }
  atomicAdd(&vsum[side * 256 + t], s);
}

// cosine cost scalar
__global__ __launch_bounds__(256) void k_final(const float* __restrict__ vsum,
                                               float* __restrict__ y){
  int t = threadIdx.x, w = t >> 6, lane = t & 63;
  __shared__ float rd[3][4];
  float v1 = vsum[t]       * (1.0f / 4096.0f);
  float v2 = vsum[256 + t] * (1.0f / 4096.0f);
  float d = v1 * v2, a = v1 * v1, b = v2 * v2;
  for (int off = 32; off; off >>= 1){
    d += __shfl_xor(d, off); a += __shfl_xor(a, off); b += __shfl_xor(b, off);
  }
  if (lane == 0){ rd[0][w] = d; rd[1][w] = a; rd[2][w] = b; }
  __syncthreads();
  if (t == 0){
    float dd = rd[0][0] + rd[0][1] + rd[0][2] + rd[0][3];
    float aa = rd[1][0] + rd[1][1] + rd[1][2] + rd[1][3];
    float bb = rd[2][0] + rd[2][1] + rd[2][2] + rd[2][3];
    y[0] = 1.0f - dd / (sqrtf(aa) * sqrtf(bb) + 1e-8f);
  }
}

// final streaming pass: column alignment in natural [i][j] layout + y-fill
__global__ __launch_bounds__(256) void k_finish(const float* __restrict__ cost,
      const float* __restrict__ tau, const float* __restrict__ ypt,
      float* __restrict__ out0, float* __restrict__ outcol){
  int idx = blockIdx.x * 256 + threadIdx.x;          // float4 index
  float4 cc = ((const float4*)cost)[idx];
  float4 tt = ((const float4*)tau)[idx & 1023];
  float  y  = ypt[0];
  float4 p;
  p.x = fmaxf(-cc.x - tt.x, 0.0f);
  p.y = fmaxf(-cc.y - tt.y, 0.0f);
  p.z = fmaxf(-cc.z - tt.z, 0.0f);
  p.w = fmaxf(-cc.w - tt.w, 0.0f);
  ((float4*)outcol)[idx] = p;
  ((float4*)out0)[idx]   = make_float4(y, y, y, y);
}

extern "C" void kernel_launch(void* const* d_in, const int* in_sizes, int n_in,
                              void* d_out, int out_size, void* d_ws, size_t ws_size,
                              hipStream_t stream){
  const float* rowv = (const float*)d_in[0];   // [4096,256]
  const float* colv = (const float*)d_in[1];   // [4096,256]
  const float* cost = (const float*)d_in[2];   // [4096,4096]
  const float* W    = (const float*)d_in[3];   // [256,256]
  const float* bG   = (const float*)d_in[4];   // [256]

  float* out0    = (float*)d_out;
  float* out_row = out0 + (size_t)N * N;
  float* out_col = out0 + 2 * (size_t)N * N;

  // ws layout (float units):
  // [0,4096)       cnt          (zeroed)
  // [4096,4608)    vsum         (zeroed)
  // [4608,4672)    scnt (+pad)  (zeroed)
  // [4672,8768)    colmax       (zeroed; 0 < fmap(any real))
  // [8768,12864)   tau
  // [12864,16960)  slist
  // [16960,...)    beta(1M) alpha(1M) candv(2M) candi(2M) ypt(1)
  int*      cnt    = (int*)d_ws;
  float*    vsum   = (float*)d_ws + 4096;
  int*      scnt   = (int*)d_ws + 4608;
  unsigned* colmax = (unsigned*)d_ws + 4672;
  float*    tau    = (float*)d_ws + 8768;
  int*      slist  = (int*)d_ws + 12864;
  float*    beta   = (float*)d_ws + 16960;
  float*    alpha  = (float*)d_ws + 16960 + 1048576;
  float*    candv  = (float*)d_ws + 16960 + 2 * 1048576;
  int*      candi  = (int*)d_ws   + 16960 + 4 * 1048576;
  float*    ypt    = (float*)d_ws + 16960 + 6 * 1048576;

  hipMemsetAsync(d_ws, 0, (size_t)8768 * 4, stream);

  hipLaunchKernelGGL(k_row,     dim3(4096),  dim3(256), 0, stream,
                     cost, colv, out_row, beta, cnt, candv, candi, colmax);
  hipLaunchKernelGGL(k_suspect, dim3(16),    dim3(256), 0, stream, cnt, colmax, scnt, slist);
  hipLaunchKernelGGL(k_rescan,  dim3(64),    dim3(256), 0, stream, cost, scnt, slist, cnt, candv, candi);
  hipLaunchKernelGGL(k_coltau,  dim3(1024),  dim3(256), 0, stream, cnt, candv, candi, rowv, tau, alpha);
  hipLaunchKernelGGL(k_G,       dim3(256,2), dim3(256), 0, stream, beta, alpha, W, bG, vsum);
  hipLaunchKernelGGL(k_final,   dim3(1),     dim3(256), 0, stream, vsum, ypt);
  hipLaunchKernelGGL(k_finish,  dim3(16384), dim3(256), 0, stream, cost, tau, ypt, out0, out_col);
}